// Round 5
// baseline (319.398 us; speedup 1.0000x reference)
//
#include <hip/hip_runtime.h>
#include <hip/hip_bf16.h>

#define BATCH 8
#define NN    2048
#define FIN   512
#define FOUT  32
#define GALPHA 0.2f
#define NROW  64          // n-rows per k_main block
#define NIT   32          // 2048/64 k-intervals

typedef float  f32x4  __attribute__((ext_vector_type(4)));
typedef __bf16 bf16x8 __attribute__((ext_vector_type(8)));
typedef unsigned short u16;
typedef unsigned char  u8;
typedef u16 u16x8 __attribute__((ext_vector_type(8)));

static __device__ __forceinline__ u16 f2bf(float f) {
    __hip_bfloat16 h = __float2bfloat16(f);
    union { __hip_bfloat16 h; u16 u; } c; c.h = h; return c.u;
}
static __device__ __forceinline__ float bf2f(u16 u) {
    union { u16 u; __hip_bfloat16 h; } c; c.u = u; return __bfloat162float(c.h);
}

// K0: w1[i] = sum_o Wfc[o][i]*a1[o], w2 likewise. 1 block x 512 thr. fp32 in.
__global__ void k_w12(const float* __restrict__ Wfc,
                      const float* __restrict__ Wat,
                      float* __restrict__ w1, float* __restrict__ w2) {
    int i = threadIdx.x;
    float s1 = 0.f, s2 = 0.f;
    #pragma unroll
    for (int o = 0; o < FOUT; o++) {
        float wv = Wfc[o * FIN + i];
        s1 += wv * Wat[o];
        s2 += wv * Wat[FOUT + o];
    }
    w1[i] = s1; w2[i] = s2;
}

// K1: fused transpose + f1/f2 partial dots (verified R3/R4). grid 2048 x 256.
__global__ void k_xtf(const float* __restrict__ x,
                      const float* __restrict__ w1, const float* __restrict__ w2,
                      __hip_bfloat16* __restrict__ xt,
                      float* __restrict__ f1, float* __restrict__ f2) {
    int bx = blockIdx.x;
    int it = bx & 7, mt = (bx >> 3) & 31, b = bx >> 8;
    int m0 = mt * 64, i0 = it * 64;
    __shared__ u16 tile[64][72];
    int tt = threadIdx.x;
    int mm = tt >> 3;
    int ic = (tt & 7) * 8;
    const float* xb = x + ((size_t)b * NN + m0) * FIN + i0;
    const f32x4* w1p = (const f32x4*)(w1 + i0 + ic);
    const f32x4* w2p = (const f32x4*)(w2 + i0 + ic);
    f32x4 wA = w1p[0], wB = w1p[1], wC = w2p[0], wD = w2p[1];
    float p1[2], p2[2];
    #pragma unroll
    for (int h = 0; h < 2; h++) {
        int m = mm + h * 32;
        const f32x4* src = (const f32x4*)(xb + (size_t)m * FIN + ic);
        f32x4 v0 = src[0], v1 = src[1];
        u16x8 pk;
        float s1 = 0.f, s2 = 0.f;
        #pragma unroll
        for (int j = 0; j < 4; j++) {
            pk[j] = f2bf(v0[j]); pk[4 + j] = f2bf(v1[j]);
            s1 += v0[j] * wA[j] + v1[j] * wB[j];
            s2 += v0[j] * wC[j] + v1[j] * wD[j];
        }
        p1[h] = s1; p2[h] = s2;
        *(u16x8*)&tile[m][ic] = pk;
    }
    #pragma unroll
    for (int off = 1; off < 8; off <<= 1) {
        p1[0] += __shfl_xor(p1[0], off); p1[1] += __shfl_xor(p1[1], off);
        p2[0] += __shfl_xor(p2[0], off); p2[1] += __shfl_xor(p2[1], off);
    }
    if ((tt & 7) == 0) {
        size_t r0 = (size_t)b * NN + m0 + mm;
        atomicAdd(&f1[r0], p1[0]);      atomicAdd(&f1[r0 + 32], p1[1]);
        atomicAdd(&f2[r0], p2[0]);      atomicAdd(&f2[r0 + 32], p2[1]);
    }
    __syncthreads();
    __hip_bfloat16* xtb = xt + ((size_t)b * FIN + i0) * NN + m0;
    int mc = (tt & 7) * 8;
    #pragma unroll
    for (int h = 0; h < 2; h++) {
        int ii = (tt >> 3) + h * 32;
        u16x8 v;
        #pragma unroll
        for (int j = 0; j < 8; j++) v[j] = tile[mc + j][ii];
        *(u16x8*)(xtb + (size_t)ii * NN + mc) = v;
    }
}

// K2: bit-pack adj -> 1 bit/entry. grid 4096 x 256 (wave per row).
__global__ void k_pack(const int* __restrict__ adj, unsigned int* __restrict__ bits) {
    int row  = blockIdx.x * 4 + (threadIdx.x >> 6);
    int lane = threadIdx.x & 63;
    const int* p = adj + (size_t)row * NN + lane * 32;
    unsigned int bv = 0;
    #pragma unroll
    for (int j = 0; j < 8; j++) {
        int4 v = *(const int4*)(p + j * 4);
        bv |= (v.x != 0 ? 1u : 0u) << (j * 4 + 0);
        bv |= (v.y != 0 ? 1u : 0u) << (j * 4 + 1);
        bv |= (v.z != 0 ? 1u : 0u) << (j * 4 + 2);
        bv |= (v.w != 0 ? 1u : 0u) << (j * 4 + 3);
    }
    bits[(size_t)row * 64 + lane] = bv;
}

// K3: fused attn-gen + GEMM + softmax-normalize + ELU.
// grid 512 = 8b x 32rt x 2it -> 2 blocks/CU. 512 thr / 8 waves.
// Block: 64 rows x 256 cols; interval BK=64; manual 2x unroll (no B reg copies).
__global__ __launch_bounds__(512, 2) void k_main(
    const unsigned int* __restrict__ bits, const __hip_bfloat16* __restrict__ xt,
    const float* __restrict__ f1, const float* __restrict__ f2,
    float* __restrict__ out)
{
    const int bx = blockIdx.x;
    const int b = bx & 7, rt = (bx >> 3) & 31, it = bx >> 8;
    const int n0 = rt * NROW;
    const int i0 = it * 256;
    const int tid = threadIdx.x;
    const int lane = tid & 63, wv = tid >> 6;
    const int quad = lane >> 4, l15 = lane & 15;

    // A tile: [row][octet ^ (row&7)] u16, row stride 64 — R3/R4-verified swizzle, 0 conflicts.
    __shared__ u16 At[2][NROW * 64];     // 2 x 8 KB
    __shared__ float rs[NROW];

    // --- gen role: thread -> (row = tid>>3, octet = tid&7: 8 m-entries each) ---
    const int grow = tid >> 3;           // 0..63
    const int oct  = tid & 7;
    const u8*    bp  = (const u8*)bits + ((size_t)(b * NN) + n0 + grow) * 256 + oct; // +8/interval
    const float* f2p = f2 + b * NN + oct * 8;                                        // +64/interval
    const float  f1v = f1[b * NN + n0 + grow];
    u16* wp = &At[0][grow * 64 + ((oct ^ (grow & 7)) * 8)];
    float rpart = 0.f;

    // --- MFMA role: wave wv owns i-cols [i0 + wv*32, +32) ---
    const __hip_bfloat16* xtp = xt + ((size_t)(b * FIN) + i0 + wv * 32 + l15) * NN + quad * 8;

    f32x4 acc[4][2];
    #pragma unroll
    for (int s = 0; s < 4; s++) { acc[s][0] = (f32x4){0,0,0,0}; acc[s][1] = (f32x4){0,0,0,0}; }

    auto gen = [&](int buf, unsigned int bv, f32x4 fa, f32x4 fb) {
        u16x8 pk;
        #pragma unroll
        for (int e = 0; e < 8; e++) {
            float s  = f1v + ((e < 4) ? fa[e & 3] : fb[e & 3]);
            float ls = fmaxf(s, GALPHA * s);                 // leaky_relu
            float ev = ((bv >> e) & 1u) ? __expf(ls) : 0.f;
            u16 hb = f2bf(ev);
            rpart += bf2f(hb);                               // rowsum of bf16-rounded
            pk[e] = hb;
        }
        *(u16x8*)(wp + buf * (NROW * 64)) = pk;
    };

    auto mfma_step = [&](int buf, const bf16x8 B[2][2]) {
        #pragma unroll
        for (int ks = 0; ks < 2; ks++) {
            #pragma unroll
            for (int s = 0; s < 4; s++) {
                const int row = s * 16 + l15;
                bf16x8 Af = *(const bf16x8*)&At[buf][row * 64 + (((ks * 4 + quad) ^ (row & 7)) * 8)];
                acc[s][0] = __builtin_amdgcn_mfma_f32_16x16x32_bf16(Af, B[ks][0], acc[s][0], 0, 0, 0);
                acc[s][1] = __builtin_amdgcn_mfma_f32_16x16x32_bf16(Af, B[ks][1], acc[s][1], 0, 0, 0);
            }
        }
    };

    // prologue: gen tile 0 directly; prime input rings for tiles 1,2; B(t=0).
    {
        unsigned int b0 = bp[0];
        f32x4 ga = *(const f32x4*)(f2p);
        f32x4 gb = *(const f32x4*)(f2p + 4);
        gen(0, b0, ga, gb);
    }
    unsigned int bA = bp[8],  bB = bp[16];
    f32x4 fA0 = *(const f32x4*)(f2p + 64),  fA1 = *(const f32x4*)(f2p + 68);
    f32x4 fB0 = *(const f32x4*)(f2p + 128), fB1 = *(const f32x4*)(f2p + 132);

    bf16x8 Bc[2][2], Bn[2][2];
    #pragma unroll
    for (int ks = 0; ks < 2; ks++)
        #pragma unroll
        for (int c = 0; c < 2; c++)
            Bc[ks][c] = *(const bf16x8*)(xtp + ks * 32 + (size_t)(c * 16) * NN);
    __syncthreads();

    for (int t = 0; t < NIT; t += 2) {
        // ---- even body: tile t (buf 0), uses Bc; prefetch Bn(t+1), gen(t+1)->buf1 ----
        {
            const __hip_bfloat16* xk = xtp + (size_t)(t + 1) * 64;
            #pragma unroll
            for (int ks = 0; ks < 2; ks++) {
                Bn[ks][0] = *(const bf16x8*)(xk + ks * 32);
                Bn[ks][1] = *(const bf16x8*)(xk + ks * 32 + (size_t)16 * NN);
            }
            mfma_step(0, Bc);
            gen(1, bA, fA0, fA1);                            // tile t+1
            if (t + 3 < NIT) {                               // refill ring A: tile t+3
                bA  = bp[(t + 3) * 8];
                fA0 = *(const f32x4*)(f2p + (t + 3) * 64);
                fA1 = *(const f32x4*)(f2p + (t + 3) * 64 + 4);
            }
            asm volatile("s_waitcnt lgkmcnt(0)\ns_barrier" ::: "memory");
        }
        // ---- odd body: tile t+1 (buf 1), uses Bn; prefetch Bc(t+2), gen(t+2)->buf0 ----
        {
            if (t + 2 < NIT) {
                const __hip_bfloat16* xk = xtp + (size_t)(t + 2) * 64;
                #pragma unroll
                for (int ks = 0; ks < 2; ks++) {
                    Bc[ks][0] = *(const bf16x8*)(xk + ks * 32);
                    Bc[ks][1] = *(const bf16x8*)(xk + ks * 32 + (size_t)16 * NN);
                }
            }
            mfma_step(1, Bn);
            if (t + 2 < NIT) {
                gen(0, bB, fB0, fB1);                        // tile t+2
                if (t + 4 < NIT) {                           // refill ring B: tile t+4
                    bB  = bp[(t + 4) * 8];
                    fB0 = *(const f32x4*)(f2p + (t + 4) * 64);
                    fB1 = *(const f32x4*)(f2p + (t + 4) * 64 + 4);
                }
                asm volatile("s_waitcnt lgkmcnt(0)\ns_barrier" ::: "memory");
            }
        }
    }

    // rowsum: reduce over the 8 octet-threads of each row
    rpart += __shfl_xor(rpart, 1);
    rpart += __shfl_xor(rpart, 2);
    rpart += __shfl_xor(rpart, 4);
    if (oct == 0) rs[grow] = 1.0f / rpart;
    __syncthreads();

    // epilogue: normalize, ELU, store fp32
    #pragma unroll
    for (int s = 0; s < 4; s++) {
        #pragma unroll
        for (int r = 0; r < 4; r++) {
            const int row = s * 16 + quad * 4 + r;
            const float inv = rs[row];
            float* op = out + ((size_t)b * NN + (n0 + row)) * FIN + i0 + wv * 32 + l15;
            #pragma unroll
            for (int c = 0; c < 2; c++) {
                float v = acc[s][c][r] * inv;
                v = v > 0.f ? v : (__expf(v) - 1.f);   // elu
                op[c * 16] = v;
            }
        }
    }
}

extern "C" void kernel_launch(void* const* d_in, const int* in_sizes, int n_in,
                              void* d_out, int out_size, void* d_ws, size_t ws_size,
                              hipStream_t stream) {
    const float* x   = (const float*)d_in[0];
    const int*   adj = (const int*)d_in[1];
    const float* Wfc = (const float*)d_in[2];
    const float* Wat = (const float*)d_in[3];
    float* out = (float*)d_out;

    float* w1 = (float*)d_ws;                                   // 512
    float* w2 = w1 + 512;                                       // 512
    float* f1 = w2 + 512;                                       // 16384
    float* f2 = f1 + BATCH * NN;                                // 16384
    unsigned int* bits = (unsigned int*)(f2 + BATCH * NN);      // 4.2 MB
    __hip_bfloat16* xt = (__hip_bfloat16*)(bits + (size_t)BATCH * NN * 64);  // 16.8 MB

    hipMemsetAsync(f1, 0, (size_t)2 * BATCH * NN * sizeof(float), stream);
    hipLaunchKernelGGL(k_w12,  dim3(1),    dim3(512), 0, stream, Wfc, Wat, w1, w2);
    hipLaunchKernelGGL(k_xtf,  dim3(2048), dim3(256), 0, stream, x, w1, w2, xt, f1, f2);
    hipLaunchKernelGGL(k_pack, dim3(4096), dim3(256), 0, stream, adj, bits);
    hipLaunchKernelGGL(k_main, dim3(512),  dim3(512), 0, stream, bits, xt, f1, f2, out);
}

// Round 6
// 309.479 us; speedup vs baseline: 1.0321x; 1.0321x over previous
//
#include <hip/hip_runtime.h>
#include <hip/hip_bf16.h>

#define BATCH 8
#define NN    2048
#define FIN   512
#define FOUT  32
#define GALPHA 0.2f
#define NROW  64          // n-rows per k_main block
#define NIT   32          // 2048/64 k-slots
#define NSLOT 4           // LDS ring depth

typedef float  f32x4  __attribute__((ext_vector_type(4)));
typedef __bf16 bf16x8 __attribute__((ext_vector_type(8)));
typedef unsigned short u16;
typedef u16 u16x8 __attribute__((ext_vector_type(8)));

static __device__ __forceinline__ u16 f2bf(float f) {
    __hip_bfloat16 h = __float2bfloat16(f);
    union { __hip_bfloat16 h; u16 u; } c; c.h = h; return c.u;
}
static __device__ __forceinline__ float bf2f(u16 u) {
    union { u16 u; __hip_bfloat16 h; } c; c.u = u; return __bfloat162float(c.h);
}

// K0: w1[i] = log2e * sum_o Wfc[o][i]*a1[o] (log2-domain fold), w2 likewise.
__global__ void k_w12(const float* __restrict__ Wfc,
                      const float* __restrict__ Wat,
                      float* __restrict__ w1, float* __restrict__ w2) {
    int i = threadIdx.x;
    float s1 = 0.f, s2 = 0.f;
    #pragma unroll
    for (int o = 0; o < FOUT; o++) {
        float wv = Wfc[o * FIN + i];
        s1 += wv * Wat[o];
        s2 += wv * Wat[FOUT + o];
    }
    const float LOG2E = 1.4426950408889634f;
    w1[i] = s1 * LOG2E; w2[i] = s2 * LOG2E;
}

// K1: fused transpose + f1/f2 partial dots (verified R3-R5). grid 2048 x 256.
__global__ void k_xtf(const float* __restrict__ x,
                      const float* __restrict__ w1, const float* __restrict__ w2,
                      __hip_bfloat16* __restrict__ xt,
                      float* __restrict__ f1, float* __restrict__ f2) {
    int bx = blockIdx.x;
    int it = bx & 7, mt = (bx >> 3) & 31, b = bx >> 8;
    int m0 = mt * 64, i0 = it * 64;
    __shared__ u16 tile[64][72];
    int tt = threadIdx.x;
    int mm = tt >> 3;
    int ic = (tt & 7) * 8;
    const float* xb = x + ((size_t)b * NN + m0) * FIN + i0;
    const f32x4* w1p = (const f32x4*)(w1 + i0 + ic);
    const f32x4* w2p = (const f32x4*)(w2 + i0 + ic);
    f32x4 wA = w1p[0], wB = w1p[1], wC = w2p[0], wD = w2p[1];
    float p1[2], p2[2];
    #pragma unroll
    for (int h = 0; h < 2; h++) {
        int m = mm + h * 32;
        const f32x4* src = (const f32x4*)(xb + (size_t)m * FIN + ic);
        f32x4 v0 = src[0], v1 = src[1];
        u16x8 pk;
        float s1 = 0.f, s2 = 0.f;
        #pragma unroll
        for (int j = 0; j < 4; j++) {
            pk[j] = f2bf(v0[j]); pk[4 + j] = f2bf(v1[j]);
            s1 += v0[j] * wA[j] + v1[j] * wB[j];
            s2 += v0[j] * wC[j] + v1[j] * wD[j];
        }
        p1[h] = s1; p2[h] = s2;
        *(u16x8*)&tile[m][ic] = pk;
    }
    #pragma unroll
    for (int off = 1; off < 8; off <<= 1) {
        p1[0] += __shfl_xor(p1[0], off); p1[1] += __shfl_xor(p1[1], off);
        p2[0] += __shfl_xor(p2[0], off); p2[1] += __shfl_xor(p2[1], off);
    }
    if ((tt & 7) == 0) {
        size_t r0 = (size_t)b * NN + m0 + mm;
        atomicAdd(&f1[r0], p1[0]);      atomicAdd(&f1[r0 + 32], p1[1]);
        atomicAdd(&f2[r0], p2[0]);      atomicAdd(&f2[r0 + 32], p2[1]);
    }
    __syncthreads();
    __hip_bfloat16* xtb = xt + ((size_t)b * FIN + i0) * NN + m0;
    int mc = (tt & 7) * 8;
    #pragma unroll
    for (int h = 0; h < 2; h++) {
        int ii = (tt >> 3) + h * 32;
        u16x8 v;
        #pragma unroll
        for (int j = 0; j < 8; j++) v[j] = tile[mc + j][ii];
        *(u16x8*)(xtb + (size_t)ii * NN + mc) = v;
    }
}

// K2: bit-pack adj -> 1 bit/entry. grid 4096 x 256 (wave per row).
__global__ void k_pack(const int* __restrict__ adj, unsigned int* __restrict__ bits) {
    int row  = blockIdx.x * 4 + (threadIdx.x >> 6);
    int lane = threadIdx.x & 63;
    const int* p = adj + (size_t)row * NN + lane * 32;
    unsigned int bv = 0;
    #pragma unroll
    for (int j = 0; j < 8; j++) {
        int4 v = *(const int4*)(p + j * 4);
        bv |= (v.x != 0 ? 1u : 0u) << (j * 4 + 0);
        bv |= (v.y != 0 ? 1u : 0u) << (j * 4 + 1);
        bv |= (v.z != 0 ? 1u : 0u) << (j * 4 + 2);
        bv |= (v.w != 0 ? 1u : 0u) << (j * 4 + 3);
    }
    bits[(size_t)row * 64 + lane] = bv;
}

// K3: producer/consumer fused kernel. grid 512 = 8b x 32rt x 2it, 512 thr.
// Waves 0-3: gen attn weights into 4-slot LDS ring. Waves 4-7: MFMA.
// Sync via per-slot LDS atomic credits; ONE __syncthreads before epilogue.
__global__ __launch_bounds__(512, 4) void k_main(
    const unsigned int* __restrict__ bits, const __hip_bfloat16* __restrict__ xt,
    const float* __restrict__ f1, const float* __restrict__ f2,
    float* __restrict__ out)
{
    const int bx = blockIdx.x;
    const int b = bx & 7, rt = (bx >> 3) & 31, it = bx >> 8;
    const int n0 = rt * NROW;
    const int i0 = it * 256;
    const int tid = threadIdx.x;
    const int wv = tid >> 6;
    const int lane = tid & 63, quad = lane >> 4, l15 = lane & 15;

    __shared__ u16 At[NSLOT][NROW * 64];   // 4 x 8 KB ring, R3-verified swizzle
    __shared__ float rs[NROW];
    __shared__ int prod_done[NSLOT], cons_done[NSLOT];

    if (tid < NSLOT) { prod_done[tid] = 0; cons_done[tid] = 0; }
    __syncthreads();

    f32x4 acc[4][4];   // consumer accumulators (uniform alloc; producers don't touch)
    #pragma unroll
    for (int s = 0; s < 4; s++)
        #pragma unroll
        for (int c = 0; c < 4; c++) acc[s][c] = (f32x4){0.f, 0.f, 0.f, 0.f};

    if (wv < 4) {
        // ---------------- producer: 256 threads, 4 thr/row, 16 k-entries each ----------------
        const int row = tid >> 2;          // 0..63
        const int o2  = tid & 3;           // 16-k chunk within slot
        const u16*   bp  = (const u16*)bits + ((size_t)(b * NN) + n0 + row) * 128 + o2; // +4/slot
        const float* f2p = f2 + b * NN + o2 * 16;                                       // +64/slot
        const float  f1v = f1[b * NN + n0 + row];
        const int swz = row & 7;
        u16* wpa = &At[0][row * 64 + (((o2 * 2)     ^ swz) * 8)];
        u16* wpb = &At[0][row * 64 + (((o2 * 2 + 1) ^ swz) * 8)];
        float rpart = 0.f;

        // prefetch slot 0 inputs
        unsigned int bvN = bp[0];
        f32x4 fN0 = *(const f32x4*)(f2p),     fN1 = *(const f32x4*)(f2p + 4);
        f32x4 fN2 = *(const f32x4*)(f2p + 8), fN3 = *(const f32x4*)(f2p + 12);

        for (int t = 0; t < NIT; t++) {
            const int s = t & (NSLOT - 1);
            unsigned int bv = bvN;
            f32x4 fc[4] = {fN0, fN1, fN2, fN3};
            if (t < NIT - 1) {             // prefetch slot t+1 (in flight during gen)
                bvN = bp[(t + 1) * 4];
                const float* fp = f2p + (t + 1) * 64;
                fN0 = *(const f32x4*)(fp);     fN1 = *(const f32x4*)(fp + 4);
                fN2 = *(const f32x4*)(fp + 8); fN3 = *(const f32x4*)(fp + 12);
            }
            if (t >= NSLOT) {              // ring credit: consumers done with epoch-1?
                const int tgt = 4 * (t >> 2);
                while (__hip_atomic_load(&cons_done[s], __ATOMIC_ACQUIRE,
                                         __HIP_MEMORY_SCOPE_WORKGROUP) < tgt) {}
            }
            u16x8 pk0, pk1;
            #pragma unroll
            for (int e = 0; e < 16; e++) {
                float sc = f1v + fc[e >> 2][e & 3];
                float ls = fmaxf(sc, GALPHA * sc);            // leaky_relu (log2 domain)
                float ev = ((bv >> e) & 1u) ? __builtin_amdgcn_exp2f(ls) : 0.f;
                u16 hb = f2bf(ev);
                rpart += bf2f(hb);                            // rowsum of bf16-rounded
                if (e < 8) pk0[e] = hb; else pk1[e - 8] = hb;
            }
            *(u16x8*)(wpa + s * (NROW * 64)) = pk0;
            *(u16x8*)(wpb + s * (NROW * 64)) = pk1;
            if (lane == 0) {}
            if ((tid & 63) == 0) {}
            // release-add: emits lgkmcnt wait for the wave's ds_writes first
            if (lane == 0)
                __hip_atomic_fetch_add(&prod_done[s], 1, __ATOMIC_RELEASE,
                                       __HIP_MEMORY_SCOPE_WORKGROUP);
        }
        // rowsum across the 4 threads of each row
        rpart += __shfl_xor(rpart, 1);
        rpart += __shfl_xor(rpart, 2);
        if (o2 == 0) rs[row] = 1.0f / rpart;
    } else {
        // ---------------- consumer: wave cw owns i-cols [i0+cw*64, +64) ----------------
        const int cw = wv - 4;
        const __hip_bfloat16* xtp = xt + ((size_t)(b * FIN) + i0 + cw * 64 + l15) * NN + quad * 8;
        for (int t = 0; t < NIT; t++) {
            const int s = t & (NSLOT - 1);
            const int tgt = 4 * ((t >> 2) + 1);
            // poll first (usually ready), then issue B loads, then A ds_reads
            while (__hip_atomic_load(&prod_done[s], __ATOMIC_ACQUIRE,
                                     __HIP_MEMORY_SCOPE_WORKGROUP) < tgt) {}
            const __hip_bfloat16* xk = xtp + (size_t)t * 64;
            bf16x8 B[2][4];
            #pragma unroll
            for (int ks = 0; ks < 2; ks++)
                #pragma unroll
                for (int c = 0; c < 4; c++)
                    B[ks][c] = *(const bf16x8*)(xk + ks * 32 + (size_t)(c * 16) * NN);
            #pragma unroll
            for (int ks = 0; ks < 2; ks++) {
                #pragma unroll
                for (int st = 0; st < 4; st++) {
                    const int row = st * 16 + l15;
                    bf16x8 Af = *(const bf16x8*)&At[s][row * 64 + (((ks * 4 + quad) ^ (row & 7)) * 8)];
                    #pragma unroll
                    for (int c = 0; c < 4; c++)
                        acc[st][c] = __builtin_amdgcn_mfma_f32_16x16x32_bf16(Af, B[ks][c], acc[st][c], 0, 0, 0);
                }
            }
            // release-add: lgkmcnt wait ensures A reads retired before slot freed
            if (lane == 0)
                __hip_atomic_fetch_add(&cons_done[s], 1, __ATOMIC_RELEASE,
                                       __HIP_MEMORY_SCOPE_WORKGROUP);
        }
    }

    __syncthreads();   // rs ready; all threads reach this

    if (wv >= 4) {
        const int cw = wv - 4;
        #pragma unroll
        for (int st = 0; st < 4; st++) {
            #pragma unroll
            for (int r = 0; r < 4; r++) {
                const int row = st * 16 + quad * 4 + r;
                const float inv = rs[row];
                float* op = out + ((size_t)b * NN + (n0 + row)) * FIN + i0 + cw * 64 + l15;
                #pragma unroll
                for (int c = 0; c < 4; c++) {
                    float v = acc[st][c][r] * inv;
                    v = v > 0.f ? v : (__expf(v) - 1.f);   // elu
                    op[c * 16] = v;
                }
            }
        }
    }
}

extern "C" void kernel_launch(void* const* d_in, const int* in_sizes, int n_in,
                              void* d_out, int out_size, void* d_ws, size_t ws_size,
                              hipStream_t stream) {
    const float* x   = (const float*)d_in[0];
    const int*   adj = (const int*)d_in[1];
    const float* Wfc = (const float*)d_in[2];
    const float* Wat = (const float*)d_in[3];
    float* out = (float*)d_out;

    float* w1 = (float*)d_ws;                                   // 512
    float* w2 = w1 + 512;                                       // 512
    float* f1 = w2 + 512;                                       // 16384
    float* f2 = f1 + BATCH * NN;                                // 16384
    unsigned int* bits = (unsigned int*)(f2 + BATCH * NN);      // 4.2 MB
    __hip_bfloat16* xt = (__hip_bfloat16*)(bits + (size_t)BATCH * NN * 64);  // 16.8 MB

    hipMemsetAsync(f1, 0, (size_t)2 * BATCH * NN * sizeof(float), stream);
    hipLaunchKernelGGL(k_w12,  dim3(1),    dim3(512), 0, stream, Wfc, Wat, w1, w2);
    hipLaunchKernelGGL(k_xtf,  dim3(2048), dim3(256), 0, stream, x, w1, w2, xt, f1, f2);
    hipLaunchKernelGGL(k_pack, dim3(4096), dim3(256), 0, stream, adj, bits);
    hipLaunchKernelGGL(k_main, dim3(512),  dim3(512), 0, stream, bits, xt, f1, f2, out);
}